// Round 7
// baseline (162.894 us; speedup 1.0000x reference)
//
#include <hip/hip_runtime.h>

typedef unsigned short u16;
typedef unsigned int u32;

typedef __attribute__((ext_vector_type(8))) short short8;
typedef __attribute__((ext_vector_type(4))) float f32x4;

#define DEV static __device__ __forceinline__
#define GLOBAL_AS __attribute__((address_space(1)))
#define LDS_AS __attribute__((address_space(3)))

// f32 -> bf16 round-to-nearest-even
DEV u16 f2bf(float f) {
    u32 u = __float_as_uint(f);
    u += 0x7fffu + ((u >> 16) & 1u);
    return (u16)(u >> 16);
}
DEV float bflo(u32 u) { return __uint_as_float(u << 16); }
DEV float bfhi(u32 u) { return __uint_as_float(u & 0xffff0000u); }
DEV u32 pack2(float a, float b) { return (u32)f2bf(a) | ((u32)f2bf(b) << 16); }

// async global->LDS, 16 bytes per lane (dest = wave-uniform base + lane*16)
DEV void gload16(const u16* g, u16* l) {
    __builtin_amdgcn_global_load_lds((const GLOBAL_AS u32*)(const void*)g,
                                     (LDS_AS u32*)(void*)l, 16, 0, 0);
}

// ---------------------------------------------------------------------------
// Weight transpose + f32->bf16: W[k][n] (512x512 row-major) -> Wt[n][k] bf16.
// ---------------------------------------------------------------------------
__global__ __launch_bounds__(256) void wtrans_kernel(
    const float* __restrict__ Wq, const float* __restrict__ Wk,
    const float* __restrict__ Wv, const float* __restrict__ Wo,
    u16* __restrict__ out)
{
    __shared__ float tile[32][33];
    const float* W = (blockIdx.z == 0) ? Wq : (blockIdx.z == 1) ? Wk
                   : (blockIdx.z == 2) ? Wv : Wo;
    u16* Wt = out + (size_t)blockIdx.z * 512 * 512;
    const int n0 = blockIdx.x * 32, k0 = blockIdx.y * 32;
    const int c = threadIdx.x & 31, r0 = threadIdx.x >> 5;
#pragma unroll
    for (int i = 0; i < 4; ++i) {
        int r = r0 + i * 8;
        tile[r][c] = W[(size_t)(k0 + r) * 512 + (n0 + c)];
    }
    __syncthreads();
#pragma unroll
    for (int i = 0; i < 4; ++i) {
        int r = r0 + i * 8;
        Wt[(size_t)(n0 + r) * 512 + (k0 + c)] = f2bf(tile[c][r]);
    }
}

// ---------------------------------------------------------------------------
// GEMM: C[8192][512] = A[8192][512] @ Wt[n][k](bf16) + bias.
// m97 structure: 128x128 tile, BK=64, 4 waves (2x2), acc[4][4].
// A_F32 path: A is f32 in HBM; reg-stage (2x float4 load -> pack bf16 ->
// swizzled ds_write_b128). Pack happens ONCE per element. B always via
// global_load_lds w16 with pre-swizzled source (rule #21).
// Both paths land in identical swizzled bf16 LDS layout; read side shared.
// ---------------------------------------------------------------------------
template<bool A_F32, bool OUT_F32>
DEV void gemm_body(const void* __restrict__ Aptr, const u16* __restrict__ Wt,
                   const float* __restrict__ bias, void* __restrict__ Cptr,
                   int bm, int bn)
{
    __shared__ u16 As[128 * 64];
    __shared__ u16 Bs[128 * 64];
    char* AsB = (char*)As;
    const char* BsB = (const char*)Bs;

    const int tid = threadIdx.x;
    const int lane = tid & 63;
    const int wave = tid >> 6;
    const int wr = wave >> 1, wc = wave & 1;
    const int l15 = lane & 15, l4 = lane >> 4;
    const int m0 = bm * 128, n0 = bn * 128;

    const f32x4 fzero = {0.f, 0.f, 0.f, 0.f};
    f32x4 acc[4][4];
#pragma unroll
    for (int i = 0; i < 4; ++i)
#pragma unroll
        for (int j = 0; j < 4; ++j) acc[i][j] = fzero;

    for (int k0 = 0; k0 < 512; k0 += 64) {
        __syncthreads();  // previous-step reads done before overwrite
        if (A_F32) {
            const float* A = (const float*)Aptr;
#pragma unroll
            for (int i = 0; i < 4; ++i) {
                const int chunk = i * 256 + tid;          // [0,1024)
                const int row = chunk >> 3, ch = chunk & 7;
                const float4* p = (const float4*)(A +
                                  (size_t)(m0 + row) * 512 + k0 + ch * 8);
                const float4 v0 = p[0], v1 = p[1];
                uint4 o;
                o.x = pack2(v0.x, v0.y); o.y = pack2(v0.z, v0.w);
                o.z = pack2(v1.x, v1.y); o.w = pack2(v1.z, v1.w);
                // scatter-write with the same XOR the read side uses
                *(uint4*)(AsB + row * 128 + ((ch ^ (row & 7)) << 4)) = o;
            }
#pragma unroll
            for (int i = 0; i < 4; ++i) {
                const int chunk = i * 256 + tid;
                const int row = chunk >> 3;
                const int ccs = (chunk & 7) ^ (row & 7);  // pre-swizzled src
                gload16(Wt + (size_t)(n0 + row) * 512 + k0 + ccs * 8,
                        &Bs[chunk * 8]);
            }
        } else {
            const u16* A = (const u16*)Aptr;
#pragma unroll
            for (int i = 0; i < 4; ++i) {
                const int chunk = i * 256 + tid;
                const int row = chunk >> 3;
                const int ccs = (chunk & 7) ^ (row & 7);
                gload16(A + (size_t)(m0 + row) * 512 + k0 + ccs * 8,
                        &As[chunk * 8]);
                gload16(Wt + (size_t)(n0 + row) * 512 + k0 + ccs * 8,
                        &Bs[chunk * 8]);
            }
        }
        __syncthreads();  // drains vmcnt + lgkmcnt

#pragma unroll
        for (int kk = 0; kk < 2; ++kk) {
            short8 af[4], bf[4];
#pragma unroll
            for (int mi = 0; mi < 4; ++mi) {
                const int row = wr * 64 + mi * 16 + l15;
                const int cc = (kk * 4 + l4) ^ (row & 7);
                af[mi] = *(const short8*)(AsB + row * 128 + cc * 16);
            }
#pragma unroll
            for (int ni = 0; ni < 4; ++ni) {
                const int row = wc * 64 + ni * 16 + l15;
                const int cc = (kk * 4 + l4) ^ (row & 7);
                bf[ni] = *(const short8*)(BsB + row * 128 + cc * 16);
            }
#pragma unroll
            for (int mi = 0; mi < 4; ++mi)
#pragma unroll
                for (int ni = 0; ni < 4; ++ni)
                    acc[mi][ni] = __builtin_amdgcn_mfma_f32_16x16x32_bf16(
                        af[mi], bf[ni], acc[mi][ni], 0, 0, 0);
        }
    }

    // epilogue: C/D layout col=lane&15, row=(lane>>4)*4+reg  [m89/m91]
#pragma unroll
    for (int ni = 0; ni < 4; ++ni) {
        const int n = n0 + wc * 64 + ni * 16 + l15;
        const float bv = bias[n];
#pragma unroll
        for (int mi = 0; mi < 4; ++mi) {
            const int mb = m0 + wr * 64 + mi * 16 + l4 * 4;
#pragma unroll
            for (int r = 0; r < 4; ++r) {
                const float v = acc[mi][ni][r] + bv;
                if (OUT_F32)
                    ((float*)Cptr)[(size_t)(mb + r) * 512 + n] = v;
                else
                    ((u16*)Cptr)[(size_t)(mb + r) * 512 + n] = f2bf(v);
            }
        }
    }
}

// XCD swizzle: 8 XCDs get 32 contiguous blocks each; bn cycles fastest so a
// bm's A panel and the whole B matrix stay L2-resident per XCD.
DEV void remap_block(int id, int& bm, int& bn)
{
    const int swz = (id & 7) * 32 + (id >> 3);
    bn = swz & 3;
    bm = swz >> 2;
}

__global__ __launch_bounds__(256) void gemm_qkv_kernel(
    const float* __restrict__ q_in, const float* __restrict__ k_in,
    const float* __restrict__ v_in, const u16* __restrict__ Wt3,
    const float* __restrict__ bq, const float* __restrict__ bk,
    const float* __restrict__ bv,
    u16* __restrict__ Qo, u16* __restrict__ Ko, u16* __restrict__ Vo)
{
    const int mat = blockIdx.y;
    const float* A = (mat == 0) ? q_in : (mat == 1) ? k_in : v_in;
    const u16* W = Wt3 + (size_t)mat * 512 * 512;
    const float* bias = (mat == 0) ? bq : (mat == 1) ? bk : bv;
    u16* C = (mat == 0) ? Qo : (mat == 1) ? Ko : Vo;
    int bm, bn; remap_block(blockIdx.x, bm, bn);
    gemm_body<true, false>(A, W, bias, C, bm, bn);
}

__global__ __launch_bounds__(256) void gemm_out_kernel(
    const u16* __restrict__ Xb, const u16* __restrict__ Wto,
    const float* __restrict__ bo, float* __restrict__ out)
{
    int bm, bn; remap_block(blockIdx.x, bm, bn);
    gemm_body<false, true>(Xb, Wto, bo, out, bm, bn);
}

// ---------------------------------------------------------------------------
// MFMA banded attention, window 31 (r2=15), zero-padded edges.
// Block: 128 q-rows, 4 waves x 32 rows. Per wave: 62-key window padded to 64.
// QK^T (16 mfma) -> band-masked wave-parallel softmax -> P(bf16) via LDS ->
// PV (16 mfma vs transposed V) -> in-register normalize -> coalesced store.
// Zero-padded edge keys give score exactly 0 and PARTICIPATE in softmax
// (matches nn.Unfold); outside-band slots are -inf (excluded).
// Vt row stride = 384 B (24 chunk slots): the swizzle cs = (cv&24)|((cv&7)^
// (d&7)) maps the partial third group cv in [16,20) onto cs in [16,24).
// ---------------------------------------------------------------------------
__global__ __launch_bounds__(256) void attn_kernel(
    const u16* __restrict__ Qb, const u16* __restrict__ Kb,
    const u16* __restrict__ Vb, const int* __restrict__ mask,
    u16* __restrict__ Xb)
{
    constexpr int TB = 128, R2 = 15, WR = 160;  // 158 staged + 2 pad
    constexpr int VS = 384;                     // Vt row stride in bytes
    __shared__ u16 Ks[WR * 64];        // [kr][d] swizzled, 20 KB
    __shared__ u16 Qs[TB * 64];        // [r][d] swizzled, 16 KB; reused as P/O
    __shared__ u16 Vt[64 * (VS / 2)];  // [d][kr] swizzled, 24 KB
    char* KsB = (char*)Ks;
    char* QsB = (char*)Qs;
    char* VtB = (char*)Vt;

    const int tid = threadIdx.x;
    const int blk = blockIdx.x;              // ((b*8 + h)*16 + tb)
    const int tb = blk & 15, h = (blk >> 4) & 7, b = blk >> 7;
    const int T0 = tb * TB;
    const int G0 = T0 - R2;
    const size_t hbase = (size_t)b * (2048 * 512) + h * 64;

    // ---- stage K (row-major, swizzled) and V (transposed, swizzled) ----
    for (int u = tid; u < WR * 8; u += 256) {
        const int r = u >> 3, c = u & 7;
        const int g = G0 + r;
        uint4 kv = make_uint4(0, 0, 0, 0), vv = make_uint4(0, 0, 0, 0);
        if (g >= 0 && g < 2048) {
            const size_t off = hbase + (size_t)g * 512 + c * 8;
            kv = *(const uint4*)(Kb + off);
            vv = *(const uint4*)(Vb + off);
        }
        *(uint4*)(KsB + r * 128 + ((c ^ (r & 7)) << 4)) = kv;
        // scatter V transposed: element (kr=r, d=c*8+i) -> Vt[d][r]
        const int cv = r >> 3, relem = r & 7;
        const u16 vs[8] = {
            (u16)(vv.x & 0xffff), (u16)(vv.x >> 16),
            (u16)(vv.y & 0xffff), (u16)(vv.y >> 16),
            (u16)(vv.z & 0xffff), (u16)(vv.z >> 16),
            (u16)(vv.w & 0xffff), (u16)(vv.w >> 16)};
#pragma unroll
        for (int i = 0; i < 8; ++i) {
            const int d = c * 8 + i;
            const int cs = (cv & 24) | ((cv & 7) ^ (d & 7));
            *(u16*)(VtB + d * VS + cs * 16 + relem * 2) = vs[i];
        }
    }
    // ---- stage Q (row-major, swizzled) ----
    for (int u = tid; u < TB * 8; u += 256) {
        const int r = u >> 3, c = u & 7;
        const uint4 qv = *(const uint4*)(Qb + hbase + (size_t)(T0 + r) * 512 + c * 8);
        *(uint4*)(QsB + r * 128 + ((c ^ (r & 7)) << 4)) = qv;
    }
    __syncthreads();

    const int lane = tid & 63;
    const int w = tid >> 6;
    const int l15 = lane & 15, l4 = lane >> 4;
    const int wrow0 = w * 32;                 // wave's first q-row (block-local)
    char* Pw = QsB + wrow0 * 128;             // per-wave 4 KB P/O region

    // ---- QK^T ----
    short8 aq[2][2], bk_[4][2];
#pragma unroll
    for (int mt = 0; mt < 2; ++mt)
#pragma unroll
        for (int kk = 0; kk < 2; ++kk) {
            const int r = wrow0 + mt * 16 + l15;
            const int cc = (kk * 4 + l4) ^ (r & 7);
            aq[mt][kk] = *(const short8*)(QsB + r * 128 + cc * 16);
        }
#pragma unroll
    for (int nt = 0; nt < 4; ++nt)
#pragma unroll
        for (int kk = 0; kk < 2; ++kk) {
            const int kr = wrow0 + nt * 16 + l15;
            const int cc = (kk * 4 + l4) ^ (kr & 7);
            bk_[nt][kk] = *(const short8*)(KsB + kr * 128 + cc * 16);
        }
    const f32x4 fzero = {0.f, 0.f, 0.f, 0.f};
    f32x4 s[2][4];
#pragma unroll
    for (int mt = 0; mt < 2; ++mt)
#pragma unroll
        for (int nt = 0; nt < 4; ++nt) {
            s[mt][nt] = fzero;
#pragma unroll
            for (int kk = 0; kk < 2; ++kk)
                s[mt][nt] = __builtin_amdgcn_mfma_f32_16x16x32_bf16(
                    aq[mt][kk], bk_[nt][kk], s[mt][nt], 0, 0, 0);
        }

    // ---- band-masked softmax (rows r=mt*16+l4*4+reg; cols jj=nt*16+l15) ----
    float inv_[2][4];
#pragma unroll
    for (int mt = 0; mt < 2; ++mt) {
#pragma unroll
        for (int reg = 0; reg < 4; ++reg) {
            const int r = mt * 16 + l4 * 4 + reg;  // wave-local q-row
            float pv[4];
            float mx = -1e30f;
#pragma unroll
            for (int nt = 0; nt < 4; ++nt) {
                const int jj = nt * 16 + l15;
                float sv = s[mt][nt][reg] * 0.125f;     // 1/sqrt(64)
                sv = (jj >= r && jj <= r + 30) ? sv : -1e30f;
                pv[nt] = sv;
                mx = fmaxf(mx, sv);
            }
            mx = fmaxf(mx, __shfl_xor(mx, 1));
            mx = fmaxf(mx, __shfl_xor(mx, 2));
            mx = fmaxf(mx, __shfl_xor(mx, 4));
            mx = fmaxf(mx, __shfl_xor(mx, 8));
            float sum = 0.f;
#pragma unroll
            for (int nt = 0; nt < 4; ++nt) {
                const float p = __expf(pv[nt] - mx);
                pv[nt] = p;
                sum += p;
            }
            sum += __shfl_xor(sum, 1);
            sum += __shfl_xor(sum, 2);
            sum += __shfl_xor(sum, 4);
            sum += __shfl_xor(sum, 8);
            inv_[mt][reg] = 1.0f / sum;
            // write P (bf16) into per-wave region, A-frag swizzled layout
#pragma unroll
            for (int nt = 0; nt < 4; ++nt) {
                const int jj = nt * 16 + l15;
                const int cc = (jj >> 3) ^ (r & 7);
                *(u16*)(Pw + r * 128 + cc * 16 + (jj & 7) * 2) = f2bf(pv[nt]);
            }
        }
    }

    // ---- PV:  O[r][d] = P[r][jj] * Vt[d][jj] ----
    short8 pa[2][2], bv[4][2];
#pragma unroll
    for (int mt = 0; mt < 2; ++mt)
#pragma unroll
        for (int kk = 0; kk < 2; ++kk) {
            const int r = mt * 16 + l15;
            const int cc = (kk * 4 + l4) ^ (r & 7);
            pa[mt][kk] = *(const short8*)(Pw + r * 128 + cc * 16);
        }
#pragma unroll
    for (int dt = 0; dt < 4; ++dt)
#pragma unroll
        for (int kk = 0; kk < 2; ++kk) {
            const int d = dt * 16 + l15;
            const int c = w * 4 + kk * 4 + l4;        // key chunk in [0,20)
            const int cs = (c & 24) | ((c & 7) ^ (d & 7));
            bv[dt][kk] = *(const short8*)(VtB + d * VS + cs * 16);
        }
    f32x4 o[2][4];
#pragma unroll
    for (int mt = 0; mt < 2; ++mt)
#pragma unroll
        for (int dt = 0; dt < 4; ++dt) {
            o[mt][dt] = fzero;
#pragma unroll
            for (int kk = 0; kk < 2; ++kk)
                o[mt][dt] = __builtin_amdgcn_mfma_f32_16x16x32_bf16(
                    pa[mt][kk], bv[dt][kk], o[mt][dt], 0, 0, 0);
        }

    // ---- normalize (+post-softmax mask) and store via LDS for coalescing ----
#pragma unroll
    for (int mt = 0; mt < 2; ++mt)
#pragma unroll
        for (int reg = 0; reg < 4; ++reg) {
            const int r = mt * 16 + l4 * 4 + reg;
            const int t = T0 + wrow0 + r;
            float iv = inv_[mt][reg];
            if (mask[b * 2048 + t] == 0) iv = 0.f;
#pragma unroll
            for (int dt = 0; dt < 4; ++dt) {
                const int d = dt * 16 + l15;
                const int cc = (d >> 3) ^ (r & 7);
                *(u16*)(Pw + r * 128 + cc * 16 + (d & 7) * 2) =
                    f2bf(o[mt][dt][reg] * iv);
            }
        }
#pragma unroll
    for (int it = 0; it < 4; ++it) {
        const int chunk = it * 64 + lane;     // 256 chunks in wave's O tile
        const int r = chunk >> 3, c = chunk & 7;
        const uint4 ov = *(const uint4*)(Pw + r * 128 + ((c ^ (r & 7)) << 4));
        *(uint4*)(Xb + hbase + (size_t)(T0 + wrow0 + r) * 512 + c * 8) = ov;
    }
}

// ---------------------------------------------------------------------------
extern "C" void kernel_launch(void* const* d_in, const int* in_sizes, int n_in,
                              void* d_out, int out_size, void* d_ws, size_t ws_size,
                              hipStream_t stream)
{
    const float* query = (const float*)d_in[0];
    const float* key   = (const float*)d_in[1];
    const float* value = (const float*)d_in[2];
    const int*   mask  = (const int*)d_in[3];
    // d_in[4] = restrict (=31, hard-coded)
    const float* Wq = (const float*)d_in[5];
    const float* bq = (const float*)d_in[6];
    const float* Wk = (const float*)d_in[7];
    const float* bk = (const float*)d_in[8];
    const float* Wv = (const float*)d_in[9];
    const float* bv = (const float*)d_in[10];
    const float* Wo = (const float*)d_in[11];
    const float* bo = (const float*)d_in[12];

    // ws (bf16 units): Wt[4*256K] | Qb | Kb | Vb | Xb  (each 8192*512)
    constexpr size_t MSZ = (size_t)8192 * 512;
    u16* wsp = (u16*)d_ws;
    u16* Wt = wsp;
    u16* Qb = wsp + 4 * 512 * 512;
    u16* Kb = Qb + MSZ;
    u16* Vb = Kb + MSZ;
    u16* Xb = Vb + MSZ;
    (void)in_sizes; (void)n_in; (void)out_size; (void)ws_size;

    wtrans_kernel<<<dim3(16, 16, 4), 256, 0, stream>>>(Wq, Wk, Wv, Wo, Wt);
    gemm_qkv_kernel<<<dim3(256, 3), 256, 0, stream>>>(
        query, key, value, Wt, bq, bk, bv, Qb, Kb, Vb);
    attn_kernel<<<512, 256, 0, stream>>>(Qb, Kb, Vb, mask, Xb);
    gemm_out_kernel<<<256, 256, 0, stream>>>(Xb, Wt + 3 * 512 * 512, bo,
                                             (float*)d_out);
}

// Round 8
// 160.352 us; speedup vs baseline: 1.0159x; 1.0159x over previous
//
#include <hip/hip_runtime.h>

typedef unsigned short u16;
typedef unsigned int u32;

typedef __attribute__((ext_vector_type(8))) short short8;
typedef __attribute__((ext_vector_type(4))) float f32x4;

#define DEV static __device__ __forceinline__
#define GLOBAL_AS __attribute__((address_space(1)))
#define LDS_AS __attribute__((address_space(3)))

// f32 -> bf16 round-to-nearest-even
DEV u16 f2bf(float f) {
    u32 u = __float_as_uint(f);
    u += 0x7fffu + ((u >> 16) & 1u);
    return (u16)(u >> 16);
}
DEV float bflo(u32 u) { return __uint_as_float(u << 16); }
DEV float bfhi(u32 u) { return __uint_as_float(u & 0xffff0000u); }
DEV u32 pack2(float a, float b) { return (u32)f2bf(a) | ((u32)f2bf(b) << 16); }

// async global->LDS, 16 bytes per lane (dest = wave-uniform base + lane*16)
DEV void gload16(const u16* g, u16* l) {
    __builtin_amdgcn_global_load_lds((const GLOBAL_AS u32*)(const void*)g,
                                     (LDS_AS u32*)(void*)l, 16, 0, 0);
}

// ---------------------------------------------------------------------------
// Weight transpose + f32->bf16: W[k][n] (512x512 row-major) -> Wt[n][k] bf16.
// ---------------------------------------------------------------------------
__global__ __launch_bounds__(256) void wtrans_kernel(
    const float* __restrict__ Wq, const float* __restrict__ Wk,
    const float* __restrict__ Wv, const float* __restrict__ Wo,
    u16* __restrict__ out)
{
    __shared__ float tile[32][33];
    const float* W = (blockIdx.z == 0) ? Wq : (blockIdx.z == 1) ? Wk
                   : (blockIdx.z == 2) ? Wv : Wo;
    u16* Wt = out + (size_t)blockIdx.z * 512 * 512;
    const int n0 = blockIdx.x * 32, k0 = blockIdx.y * 32;
    const int c = threadIdx.x & 31, r0 = threadIdx.x >> 5;
#pragma unroll
    for (int i = 0; i < 4; ++i) {
        int r = r0 + i * 8;
        tile[r][c] = W[(size_t)(k0 + r) * 512 + (n0 + c)];
    }
    __syncthreads();
#pragma unroll
    for (int i = 0; i < 4; ++i) {
        int r = r0 + i * 8;
        Wt[(size_t)(n0 + r) * 512 + (k0 + c)] = f2bf(tile[c][r]);
    }
}

// ---------------------------------------------------------------------------
// GEMM: C[8192][512] = A[8192][512] @ Wt[n][k](bf16) + bias.
// m97 structure: 128x128 tile, BK=64, 4 waves (2x2), acc[4][4].
// A_F32 path (T14 async-STAGE split, round-7 post-mortem): tile k's f32 A
// data is loaded into REGISTERS during step k-1 (prologue for k=0); the
// staging phase only packs regs -> swizzled ds_write (no HBM wait), issues
// B's global_load_lds FIRST (earliest fetch start), then issues the A-loads
// for k+1 which fly across the barrier/MFMA. Collapses the two serial HBM
// latencies per K-step that made the round-7 version 43 us.
// B always via global_load_lds w16 with pre-swizzled source (rule #21).
// ---------------------------------------------------------------------------
template<bool A_F32, bool OUT_F32>
DEV void gemm_body(const void* __restrict__ Aptr, const u16* __restrict__ Wt,
                   const float* __restrict__ bias, void* __restrict__ Cptr,
                   int bm, int bn)
{
    __shared__ u16 As[128 * 64];
    __shared__ u16 Bs[128 * 64];
    char* AsB = (char*)As;
    const char* BsB = (const char*)Bs;

    const int tid = threadIdx.x;
    const int lane = tid & 63;
    const int wave = tid >> 6;
    const int wr = wave >> 1, wc = wave & 1;
    const int l15 = lane & 15, l4 = lane >> 4;
    const int m0 = bm * 128, n0 = bn * 128;

    const f32x4 fzero = {0.f, 0.f, 0.f, 0.f};
    f32x4 acc[4][4];
#pragma unroll
    for (int i = 0; i < 4; ++i)
#pragma unroll
        for (int j = 0; j < 4; ++j) acc[i][j] = fzero;

    float4 pa[4][2];  // A_F32 only: next tile's f32 data (static-indexed)
    if (A_F32) {
        const float* A = (const float*)Aptr;
#pragma unroll
        for (int i = 0; i < 4; ++i) {
            const int chunk = i * 256 + tid;
            const int row = chunk >> 3, ch = chunk & 7;
            const float4* p = (const float4*)(A + (size_t)(m0 + row) * 512 + ch * 8);
            pa[i][0] = p[0]; pa[i][1] = p[1];
        }
    }

    for (int k0 = 0; k0 < 512; k0 += 64) {
        __syncthreads();  // previous-step LDS reads done before overwrite
        if (A_F32) {
            const float* A = (const float*)Aptr;
            // B first: starts its HBM fetch under the pack VALU work
#pragma unroll
            for (int i = 0; i < 4; ++i) {
                const int chunk = i * 256 + tid;
                const int row = chunk >> 3;
                const int ccs = (chunk & 7) ^ (row & 7);  // pre-swizzled src
                gload16(Wt + (size_t)(n0 + row) * 512 + k0 + ccs * 8,
                        &Bs[chunk * 8]);
            }
            // pack tile k (regs already resident -> no HBM wait here)
#pragma unroll
            for (int i = 0; i < 4; ++i) {
                const int chunk = i * 256 + tid;
                const int row = chunk >> 3, ch = chunk & 7;
                uint4 o;
                o.x = pack2(pa[i][0].x, pa[i][0].y);
                o.y = pack2(pa[i][0].z, pa[i][0].w);
                o.z = pack2(pa[i][1].x, pa[i][1].y);
                o.w = pack2(pa[i][1].z, pa[i][1].w);
                *(uint4*)(AsB + row * 128 + ((ch ^ (row & 7)) << 4)) = o;
            }
            // prefetch tile k+1 into the freed regs; overlaps drain + MFMA
            if (k0 + 64 < 512) {
#pragma unroll
                for (int i = 0; i < 4; ++i) {
                    const int chunk = i * 256 + tid;
                    const int row = chunk >> 3, ch = chunk & 7;
                    const float4* p = (const float4*)(A +
                        (size_t)(m0 + row) * 512 + (k0 + 64) + ch * 8);
                    pa[i][0] = p[0]; pa[i][1] = p[1];
                }
            }
        } else {
            const u16* A = (const u16*)Aptr;
#pragma unroll
            for (int i = 0; i < 4; ++i) {
                const int chunk = i * 256 + tid;
                const int row = chunk >> 3;
                const int ccs = (chunk & 7) ^ (row & 7);
                gload16(A + (size_t)(m0 + row) * 512 + k0 + ccs * 8,
                        &As[chunk * 8]);
                gload16(Wt + (size_t)(n0 + row) * 512 + k0 + ccs * 8,
                        &Bs[chunk * 8]);
            }
        }
        __syncthreads();  // drains ds_write (lgkm) + gload_lds (vmcnt)

#pragma unroll
        for (int kk = 0; kk < 2; ++kk) {
            short8 af[4], bf[4];
#pragma unroll
            for (int mi = 0; mi < 4; ++mi) {
                const int row = wr * 64 + mi * 16 + l15;
                const int cc = (kk * 4 + l4) ^ (row & 7);
                af[mi] = *(const short8*)(AsB + row * 128 + cc * 16);
            }
#pragma unroll
            for (int ni = 0; ni < 4; ++ni) {
                const int row = wc * 64 + ni * 16 + l15;
                const int cc = (kk * 4 + l4) ^ (row & 7);
                bf[ni] = *(const short8*)(BsB + row * 128 + cc * 16);
            }
#pragma unroll
            for (int mi = 0; mi < 4; ++mi)
#pragma unroll
                for (int ni = 0; ni < 4; ++ni)
                    acc[mi][ni] = __builtin_amdgcn_mfma_f32_16x16x32_bf16(
                        af[mi], bf[ni], acc[mi][ni], 0, 0, 0);
        }
    }

    // epilogue: C/D layout col=lane&15, row=(lane>>4)*4+reg  [m89/m91]
#pragma unroll
    for (int ni = 0; ni < 4; ++ni) {
        const int n = n0 + wc * 64 + ni * 16 + l15;
        const float bv = bias[n];
#pragma unroll
        for (int mi = 0; mi < 4; ++mi) {
            const int mb = m0 + wr * 64 + mi * 16 + l4 * 4;
#pragma unroll
            for (int r = 0; r < 4; ++r) {
                const float v = acc[mi][ni][r] + bv;
                if (OUT_F32)
                    ((float*)Cptr)[(size_t)(mb + r) * 512 + n] = v;
                else
                    ((u16*)Cptr)[(size_t)(mb + r) * 512 + n] = f2bf(v);
            }
        }
    }
}

// XCD swizzle: 8 XCDs get 32 contiguous blocks each; bn cycles fastest so a
// bm's A panel and the whole B matrix stay L2-resident per XCD.
DEV void remap_block(int id, int& bm, int& bn)
{
    const int swz = (id & 7) * 32 + (id >> 3);
    bn = swz & 3;
    bm = swz >> 2;
}

__global__ __launch_bounds__(256) void gemm_qkv_kernel(
    const float* __restrict__ q_in, const float* __restrict__ k_in,
    const float* __restrict__ v_in, const u16* __restrict__ Wt3,
    const float* __restrict__ bq, const float* __restrict__ bk,
    const float* __restrict__ bv,
    u16* __restrict__ Qo, u16* __restrict__ Ko, u16* __restrict__ Vo)
{
    const int mat = blockIdx.y;
    const float* A = (mat == 0) ? q_in : (mat == 1) ? k_in : v_in;
    const u16* W = Wt3 + (size_t)mat * 512 * 512;
    const float* bias = (mat == 0) ? bq : (mat == 1) ? bk : bv;
    u16* C = (mat == 0) ? Qo : (mat == 1) ? Ko : Vo;
    int bm, bn; remap_block(blockIdx.x, bm, bn);
    gemm_body<true, false>(A, W, bias, C, bm, bn);
}

__global__ __launch_bounds__(256) void gemm_out_kernel(
    const u16* __restrict__ Xb, const u16* __restrict__ Wto,
    const float* __restrict__ bo, float* __restrict__ out)
{
    int bm, bn; remap_block(blockIdx.x, bm, bn);
    gemm_body<false, true>(Xb, Wto, bo, out, bm, bn);
}

// ---------------------------------------------------------------------------
// MFMA banded attention, window 31 (r2=15), zero-padded edges.
// Block: 128 q-rows, 4 waves x 32 rows. Per wave: 62-key window padded to 64.
// QK^T (16 mfma) -> band-masked wave-parallel softmax -> P(bf16) via LDS ->
// PV (16 mfma vs transposed V) -> in-register normalize -> coalesced store.
// Zero-padded edge keys give score exactly 0 and PARTICIPATE in softmax
// (matches nn.Unfold); outside-band slots are -inf (excluded).
// Vt row stride = 384 B (24 chunk slots): the swizzle cs = (cv&24)|((cv&7)^
// (d&7)) maps the partial third group cv in [16,20) onto cs in [16,24).
// ---------------------------------------------------------------------------
__global__ __launch_bounds__(256) void attn_kernel(
    const u16* __restrict__ Qb, const u16* __restrict__ Kb,
    const u16* __restrict__ Vb, const int* __restrict__ mask,
    u16* __restrict__ Xb)
{
    constexpr int TB = 128, R2 = 15, WR = 160;  // 158 staged + 2 pad
    constexpr int VS = 384;                     // Vt row stride in bytes
    __shared__ u16 Ks[WR * 64];        // [kr][d] swizzled, 20 KB
    __shared__ u16 Qs[TB * 64];        // [r][d] swizzled, 16 KB; reused as P/O
    __shared__ u16 Vt[64 * (VS / 2)];  // [d][kr] swizzled, 24 KB
    char* KsB = (char*)Ks;
    char* QsB = (char*)Qs;
    char* VtB = (char*)Vt;

    const int tid = threadIdx.x;
    const int blk = blockIdx.x;              // ((b*8 + h)*16 + tb)
    const int tb = blk & 15, h = (blk >> 4) & 7, b = blk >> 7;
    const int T0 = tb * TB;
    const int G0 = T0 - R2;
    const size_t hbase = (size_t)b * (2048 * 512) + h * 64;

    // ---- stage K (row-major, swizzled) and V (transposed, swizzled) ----
    for (int u = tid; u < WR * 8; u += 256) {
        const int r = u >> 3, c = u & 7;
        const int g = G0 + r;
        uint4 kv = make_uint4(0, 0, 0, 0), vv = make_uint4(0, 0, 0, 0);
        if (g >= 0 && g < 2048) {
            const size_t off = hbase + (size_t)g * 512 + c * 8;
            kv = *(const uint4*)(Kb + off);
            vv = *(const uint4*)(Vb + off);
        }
        *(uint4*)(KsB + r * 128 + ((c ^ (r & 7)) << 4)) = kv;
        // scatter V transposed: element (kr=r, d=c*8+i) -> Vt[d][r]
        const int cv = r >> 3, relem = r & 7;
        const u16 vs[8] = {
            (u16)(vv.x & 0xffff), (u16)(vv.x >> 16),
            (u16)(vv.y & 0xffff), (u16)(vv.y >> 16),
            (u16)(vv.z & 0xffff), (u16)(vv.z >> 16),
            (u16)(vv.w & 0xffff), (u16)(vv.w >> 16)};
#pragma unroll
        for (int i = 0; i < 8; ++i) {
            const int d = c * 8 + i;
            const int cs = (cv & 24) | ((cv & 7) ^ (d & 7));
            *(u16*)(VtB + d * VS + cs * 16 + relem * 2) = vs[i];
        }
    }
    // ---- stage Q (row-major, swizzled) ----
    for (int u = tid; u < TB * 8; u += 256) {
        const int r = u >> 3, c = u & 7;
        const uint4 qv = *(const uint4*)(Qb + hbase + (size_t)(T0 + r) * 512 + c * 8);
        *(uint4*)(QsB + r * 128 + ((c ^ (r & 7)) << 4)) = qv;
    }
    __syncthreads();

    const int lane = tid & 63;
    const int w = tid >> 6;
    const int l15 = lane & 15, l4 = lane >> 4;
    const int wrow0 = w * 32;                 // wave's first q-row (block-local)
    char* Pw = QsB + wrow0 * 128;             // per-wave 4 KB P/O region

    // ---- QK^T ----
    short8 aq[2][2], bk_[4][2];
#pragma unroll
    for (int mt = 0; mt < 2; ++mt)
#pragma unroll
        for (int kk = 0; kk < 2; ++kk) {
            const int r = wrow0 + mt * 16 + l15;
            const int cc = (kk * 4 + l4) ^ (r & 7);
            aq[mt][kk] = *(const short8*)(QsB + r * 128 + cc * 16);
        }
#pragma unroll
    for (int nt = 0; nt < 4; ++nt)
#pragma unroll
        for (int kk = 0; kk < 2; ++kk) {
            const int kr = wrow0 + nt * 16 + l15;
            const int cc = (kk * 4 + l4) ^ (kr & 7);
            bk_[nt][kk] = *(const short8*)(KsB + kr * 128 + cc * 16);
        }
    const f32x4 fzero = {0.f, 0.f, 0.f, 0.f};
    f32x4 s[2][4];
#pragma unroll
    for (int mt = 0; mt < 2; ++mt)
#pragma unroll
        for (int nt = 0; nt < 4; ++nt) {
            s[mt][nt] = fzero;
#pragma unroll
            for (int kk = 0; kk < 2; ++kk)
                s[mt][nt] = __builtin_amdgcn_mfma_f32_16x16x32_bf16(
                    aq[mt][kk], bk_[nt][kk], s[mt][nt], 0, 0, 0);
        }

    // ---- band-masked softmax (rows r=mt*16+l4*4+reg; cols jj=nt*16+l15) ----
    float inv_[2][4];
#pragma unroll
    for (int mt = 0; mt < 2; ++mt) {
#pragma unroll
        for (int reg = 0; reg < 4; ++reg) {
            const int r = mt * 16 + l4 * 4 + reg;  // wave-local q-row
            float pv[4];
            float mx = -1e30f;
#pragma unroll
            for (int nt = 0; nt < 4; ++nt) {
                const int jj = nt * 16 + l15;
                float sv = s[mt][nt][reg] * 0.125f;     // 1/sqrt(64)
                sv = (jj >= r && jj <= r + 30) ? sv : -1e30f;
                pv[nt] = sv;
                mx = fmaxf(mx, sv);
            }
            mx = fmaxf(mx, __shfl_xor(mx, 1));
            mx = fmaxf(mx, __shfl_xor(mx, 2));
            mx = fmaxf(mx, __shfl_xor(mx, 4));
            mx = fmaxf(mx, __shfl_xor(mx, 8));
            float sum = 0.f;
#pragma unroll
            for (int nt = 0; nt < 4; ++nt) {
                const float p = __expf(pv[nt] - mx);
                pv[nt] = p;
                sum += p;
            }
            sum += __shfl_xor(sum, 1);
            sum += __shfl_xor(sum, 2);
            sum += __shfl_xor(sum, 4);
            sum += __shfl_xor(sum, 8);
            inv_[mt][reg] = 1.0f / sum;
            // write P (bf16) into per-wave region, A-frag swizzled layout
#pragma unroll
            for (int nt = 0; nt < 4; ++nt) {
                const int jj = nt * 16 + l15;
                const int cc = (jj >> 3) ^ (r & 7);
                *(u16*)(Pw + r * 128 + cc * 16 + (jj & 7) * 2) = f2bf(pv[nt]);
            }
        }
    }

    // ---- PV:  O[r][d] = P[r][jj] * Vt[d][jj] ----
    short8 pa[2][2], bv[4][2];
#pragma unroll
    for (int mt = 0; mt < 2; ++mt)
#pragma unroll
        for (int kk = 0; kk < 2; ++kk) {
            const int r = mt * 16 + l15;
            const int cc = (kk * 4 + l4) ^ (r & 7);
            pa[mt][kk] = *(const short8*)(Pw + r * 128 + cc * 16);
        }
#pragma unroll
    for (int dt = 0; dt < 4; ++dt)
#pragma unroll
        for (int kk = 0; kk < 2; ++kk) {
            const int d = dt * 16 + l15;
            const int c = w * 4 + kk * 4 + l4;        // key chunk in [0,20)
            const int cs = (c & 24) | ((c & 7) ^ (d & 7));
            bv[dt][kk] = *(const short8*)(VtB + d * VS + cs * 16);
        }
    f32x4 o[2][4];
#pragma unroll
    for (int mt = 0; mt < 2; ++mt)
#pragma unroll
        for (int dt = 0; dt < 4; ++dt) {
            o[mt][dt] = fzero;
#pragma unroll
            for (int kk = 0; kk < 2; ++kk)
                o[mt][dt] = __builtin_amdgcn_mfma_f32_16x16x32_bf16(
                    pa[mt][kk], bv[dt][kk], o[mt][dt], 0, 0, 0);
        }

    // ---- normalize (+post-softmax mask) and store via LDS for coalescing ----
#pragma unroll
    for (int mt = 0; mt < 2; ++mt)
#pragma unroll
        for (int reg = 0; reg < 4; ++reg) {
            const int r = mt * 16 + l4 * 4 + reg;
            const int t = T0 + wrow0 + r;
            float iv = inv_[mt][reg];
            if (mask[b * 2048 + t] == 0) iv = 0.f;
#pragma unroll
            for (int dt = 0; dt < 4; ++dt) {
                const int d = dt * 16 + l15;
                const int cc = (d >> 3) ^ (r & 7);
                *(u16*)(Pw + r * 128 + cc * 16 + (d & 7) * 2) =
                    f2bf(o[mt][dt][reg] * iv);
            }
        }
#pragma unroll
    for (int it = 0; it < 4; ++it) {
        const int chunk = it * 64 + lane;     // 256 chunks in wave's O tile
        const int r = chunk >> 3, c = chunk & 7;
        const uint4 ov = *(const uint4*)(Pw + r * 128 + ((c ^ (r & 7)) << 4));
        *(uint4*)(Xb + hbase + (size_t)(T0 + wrow0 + r) * 512 + c * 8) = ov;
    }
}

// ---------------------------------------------------------------------------
extern "C" void kernel_launch(void* const* d_in, const int* in_sizes, int n_in,
                              void* d_out, int out_size, void* d_ws, size_t ws_size,
                              hipStream_t stream)
{
    const float* query = (const float*)d_in[0];
    const float* key   = (const float*)d_in[1];
    const float* value = (const float*)d_in[2];
    const int*   mask  = (const int*)d_in[3];
    // d_in[4] = restrict (=31, hard-coded)
    const float* Wq = (const float*)d_in[5];
    const float* bq = (const float*)d_in[6];
    const float* Wk = (const float*)d_in[7];
    const float* bk = (const float*)d_in[8];
    const float* Wv = (const float*)d_in[9];
    const float* bv = (const float*)d_in[10];
    const float* Wo = (const float*)d_in[11];
    const float* bo = (const float*)d_in[12];

    // ws (bf16 units): Wt[4*256K] | Qb | Kb | Vb | Xb  (each 8192*512)
    constexpr size_t MSZ = (size_t)8192 * 512;
    u16* wsp = (u16*)d_ws;
    u16* Wt = wsp;
    u16* Qb = wsp + 4 * 512 * 512;
    u16* Kb = Qb + MSZ;
    u16* Vb = Kb + MSZ;
    u16* Xb = Vb + MSZ;
    (void)in_sizes; (void)n_in; (void)out_size; (void)ws_size;

    wtrans_kernel<<<dim3(16, 16, 4), 256, 0, stream>>>(Wq, Wk, Wv, Wo, Wt);
    gemm_qkv_kernel<<<dim3(256, 3), 256, 0, stream>>>(
        query, key, value, Wt, bq, bk, bv, Qb, Kb, Vb);
    attn_kernel<<<512, 256, 0, stream>>>(Qb, Kb, Vb, mask, Xb);
    gemm_out_kernel<<<256, 256, 0, stream>>>(Xb, Wt + 3 * 512 * 512, bo,
                                             (float*)d_out);
}